// Round 13
// baseline (705.083 us; speedup 1.0000x reference)
//
#include <hip/hip_runtime.h>

#define Wd 256
#define Hd 256
#define Nn 65536   // H*W
#define Cc 64
#define Vv 4
#define Bb 2
#define BVn 8
#define NREC ((size_t)BVn * Nn)   // 524288 = 2^19
#define EPSf 1e-8f

// ---- workspace layout (bytes) ----
#define OFF_COUNT   ((size_t)0)            // u32[524288]  2 MiB
#define OFF_OFFS    ((size_t)2  << 20)     // u32[524288]  2 MiB
#define OFF_CURS    ((size_t)4  << 20)     // u32[524288]  2 MiB
#define OFF_ROWSUM  ((size_t)6  << 20)     // u32[2048]
#define OFF_ROWBASE (((size_t)6 << 20) + 65536)
#define OFF_STAGE1  ((size_t)8  << 20)     // float4[524288] 8 MiB
#define OFF_BINNED  ((size_t)16 << 20)     // float4[524288] 8 MiB
#define OFF_FT      ((size_t)24 << 20)     // binnedF planar: 4 x [524288 x 64B] = 128 MiB
#define FT_BYTES    ((size_t)BVn * Nn * Cc * 4)
#define NEED_FULL   (OFF_FT + FT_BYTES)
#define NEED_MID    OFF_FT

// ---------------- small matrix helpers ----------------
__device__ inline void mat4_mul(const float* A, const float* B, float* C) {
#pragma unroll
  for (int i = 0; i < 4; i++)
#pragma unroll
    for (int j = 0; j < 4; j++) {
      float s = 0.f;
#pragma unroll
      for (int k = 0; k < 4; k++) s += A[i * 4 + k] * B[k * 4 + j];
      C[i * 4 + j] = s;
    }
}

__device__ inline void mat4_inv(const float* m, float* invOut) {
  float inv[16];
  inv[0] = m[5]*m[10]*m[15] - m[5]*m[11]*m[14] - m[9]*m[6]*m[15] +
           m[9]*m[7]*m[14] + m[13]*m[6]*m[11] - m[13]*m[7]*m[10];
  inv[4] = -m[4]*m[10]*m[15] + m[4]*m[11]*m[14] + m[8]*m[6]*m[15] -
           m[8]*m[7]*m[14] - m[12]*m[6]*m[11] + m[12]*m[7]*m[10];
  inv[8] = m[4]*m[9]*m[15] - m[4]*m[11]*m[13] - m[8]*m[5]*m[15] +
           m[8]*m[7]*m[13] + m[12]*m[5]*m[11] - m[12]*m[7]*m[9];
  inv[12] = -m[4]*m[9]*m[14] + m[4]*m[10]*m[13] + m[8]*m[5]*m[14] -
            m[8]*m[6]*m[13] - m[12]*m[5]*m[10] + m[12]*m[6]*m[9];
  inv[1] = -m[1]*m[10]*m[15] + m[1]*m[11]*m[14] + m[9]*m[2]*m[15] -
           m[9]*m[3]*m[14] - m[13]*m[2]*m[11] + m[13]*m[3]*m[10];
  inv[5] = m[0]*m[10]*m[15] - m[0]*m[11]*m[14] - m[8]*m[2]*m[15] +
           m[8]*m[3]*m[14] + m[12]*m[2]*m[11] - m[12]*m[3]*m[10];
  inv[9] = -m[0]*m[9]*m[15] + m[0]*m[11]*m[13] + m[8]*m[1]*m[15] -
           m[8]*m[3]*m[13] - m[12]*m[1]*m[11] + m[12]*m[3]*m[9];
  inv[13] = m[0]*m[9]*m[14] - m[0]*m[10]*m[13] - m[8]*m[1]*m[14] +
            m[8]*m[2]*m[13] + m[12]*m[1]*m[10] - m[12]*m[2]*m[9];
  inv[2] = m[1]*m[6]*m[15] - m[1]*m[7]*m[14] - m[5]*m[2]*m[15] +
           m[5]*m[3]*m[14] + m[13]*m[2]*m[7] - m[13]*m[3]*m[6];
  inv[6] = -m[0]*m[6]*m[15] + m[0]*m[7]*m[14] + m[4]*m[2]*m[15] -
           m[4]*m[3]*m[14] - m[12]*m[2]*m[7] + m[12]*m[3]*m[6];
  inv[10] = m[0]*m[5]*m[15] - m[0]*m[7]*m[13] - m[4]*m[1]*m[15] +
            m[4]*m[3]*m[13] + m[12]*m[1]*m[7] - m[12]*m[3]*m[5];
  inv[14] = -m[0]*m[5]*m[14] + m[0]*m[6]*m[13] + m[4]*m[1]*m[14] -
            m[4]*m[2]*m[13] - m[12]*m[1]*m[6] + m[12]*m[2]*m[5];
  inv[3] = -m[1]*m[6]*m[11] + m[1]*m[7]*m[10] + m[5]*m[2]*m[11] -
           m[5]*m[3]*m[10] - m[9]*m[2]*m[7] + m[9]*m[3]*m[6];
  inv[7] = m[0]*m[6]*m[11] - m[0]*m[7]*m[10] - m[4]*m[2]*m[11] +
           m[4]*m[3]*m[10] + m[8]*m[2]*m[7] - m[8]*m[3]*m[6];
  inv[11] = -m[0]*m[5]*m[11] + m[0]*m[7]*m[9] + m[4]*m[1]*m[11] -
            m[4]*m[3]*m[9] - m[8]*m[1]*m[7] + m[8]*m[3]*m[5];
  inv[15] = m[0]*m[5]*m[10] - m[0]*m[6]*m[9] - m[4]*m[1]*m[10] +
            m[4]*m[2]*m[9] + m[8]*m[1]*m[6] - m[8]*m[2]*m[5];
  float det = m[0]*inv[0] + m[1]*inv[4] + m[2]*inv[8] + m[3]*inv[12];
  det = 1.0f / det;
#pragma unroll
  for (int i = 0; i < 16; i++) invOut[i] = inv[i] * det;
}

__device__ inline void compute_T(const float* Kmat, const float* srcinv,
                                 const float* dstRT, int b, int bv, float* T) {
  float Kinv[16], M1[16], M2[16];
  mat4_inv(Kmat + b * 16, Kinv);
  mat4_mul(srcinv + bv * 16, Kinv, M1);
  mat4_mul(dstRT + b * 16, M1, M2);
  mat4_mul(Kmat + b * 16, M2, T);
}

// ---------------- K1: project, count, stage ----------------
__global__ __launch_bounds__(256) void project_count_kernel(
    const float* __restrict__ depths, const float* __restrict__ Kmat,
    const float* __restrict__ srcinv, const float* __restrict__ dstRT,
    unsigned int* __restrict__ counts, float4* __restrict__ stage1) {
  const int bv = blockIdx.x >> 8;
  const int n = ((blockIdx.x & 255) << 8) | threadIdx.x;
  const int b = bv >> 2;

  __shared__ float T[16];
  if (threadIdx.x == 0) compute_T(Kmat, srcinv, dstRT, b, bv, T);
  __syncthreads();

  const float d = depths[(size_t)bv * Nn + n];
  const float gx = (float)(n & (Wd - 1));
  const float gy = (float)(n >> 8);

  const float p0 = (T[0] * gx + T[1] * gy + T[2]) * d + T[3];
  const float p1 = (T[4] * gx + T[5] * gy + T[6]) * d + T[7];
  const float z  = (T[8] * gx + T[9] * gy + T[10]) * d + T[11];

  const float ze = z + EPSf;
  const float x = p0 / ze;
  const float y = p1 / ze;
  const float px0 = rintf(x);
  const float py0 = rintf(y);

  int bin = -1;
  if (z > EPSf && px0 >= -2.0f && px0 <= (float)(Wd + 1) &&
      py0 >= -2.0f && py0 <= (float)(Hd + 1)) {
    const int bx = min(max((int)px0, 0), Wd - 1);
    const int by = min(max((int)py0, 0), Hd - 1);
    bin = (bv << 16) | (by << 8) | bx;
    atomicAdd(&counts[bin], 1u);
  }
  float4 rec;
  rec.x = x; rec.y = y; rec.z = z; rec.w = __int_as_float(bin);
  stage1[(size_t)bv * Nn + n] = rec;
}

// ---------------- K2a: per-row sums — one wave per row ----------------
__global__ __launch_bounds__(256) void row_sum_kernel(
    const unsigned int* __restrict__ counts, unsigned int* __restrict__ rowsum) {
  const int wid = threadIdx.x >> 6;
  const int lane = threadIdx.x & 63;
  const int r = blockIdx.x * 4 + wid;  // 512 blocks x 4 waves = 2048 rows
  const uint4 c = reinterpret_cast<const uint4*>(counts + (size_t)r * 256)[lane];
  unsigned int s = c.x + c.y + c.z + c.w;
#pragma unroll
  for (int off = 32; off > 0; off >>= 1) s += __shfl_down(s, off, 64);
  if (lane == 0) rowsum[r] = s;
}

// ---------------- K2b: exclusive scan of 2048 row sums (one block) --------
__global__ __launch_bounds__(256) void scan_rows_kernel(
    const unsigned int* __restrict__ rowsum, unsigned int* __restrict__ rowbase) {
  __shared__ unsigned int part[256];
  const int t = threadIdx.x;
  unsigned int loc[8];
  unsigned int run = 0;
#pragma unroll
  for (int i = 0; i < 8; i++) {
    loc[i] = run;
    run += rowsum[t * 8 + i];
  }
  part[t] = run;
  __syncthreads();
  for (int off = 1; off < 256; off <<= 1) {
    unsigned int x = part[t];
    unsigned int y = (t >= off) ? part[t - off] : 0u;
    __syncthreads();
    part[t] = x + y;
    __syncthreads();
  }
  const unsigned int base = (t == 0) ? 0u : part[t - 1];
#pragma unroll
  for (int i = 0; i < 8; i++) rowbase[t * 8 + i] = base + loc[i];
}

// ---------------- K2c: per-bin offsets + cursors — one wave per row -------
__global__ __launch_bounds__(256) void bin_offsets_kernel(
    const unsigned int* __restrict__ counts, const unsigned int* __restrict__ rowbase,
    unsigned int* __restrict__ offs, unsigned int* __restrict__ curs) {
  const int wid = threadIdx.x >> 6;
  const int lane = threadIdx.x & 63;
  const int r = blockIdx.x * 4 + wid;  // 512 blocks x 4 waves = 2048 rows
  const uint4 c = reinterpret_cast<const uint4*>(counts + (size_t)r * 256)[lane];
  const unsigned int t0 = c.x;
  const unsigned int t1 = t0 + c.y;
  const unsigned int t2 = t1 + c.z;
  const unsigned int t3 = t2 + c.w;  // quad inclusive total
  unsigned int inc = t3;
#pragma unroll
  for (int off = 1; off < 64; off <<= 1) {
    const unsigned int v = __shfl_up(inc, off, 64);
    if (lane >= off) inc += v;
  }
  const unsigned int base = rowbase[r] + inc - t3;  // exclusive prefix
  uint4 o;
  o.x = base;
  o.y = base + t0;
  o.z = base + t1;
  o.w = base + t2;
  reinterpret_cast<uint4*>(offs + (size_t)r * 256)[lane] = o;
  reinterpret_cast<uint4*>(curs + (size_t)r * 256)[lane] = o;
}

// ---------------- K3: fill binned records (+ planar feature slices) -------
// binnedF layout: 4 planes of [NREC][16 floats]; plane cg holds channels
// [cg*16, cg*16+16) of every record. Gather block cg streams plane cg
// densely (consecutive records are adjacent 64B) -> no cache-line split.
template <bool FSTAGED>
__global__ __launch_bounds__(256) void fill_kernel(
    const float* __restrict__ feats, const float4* __restrict__ stage1,
    unsigned int* __restrict__ curs, float4* __restrict__ binned,
    float4* __restrict__ binnedF) {
  const int g = blockIdx.x * 256 + threadIdx.x;  // 0..524287
  float4 rec = stage1[g];
  const int bin = __float_as_int(rec.w);
  if (bin >= 0) {
    const unsigned int slot = atomicAdd(&curs[bin], 1u);
    const int n = g & (Nn - 1);
    if (FSTAGED) {
      // rec.w = 1/(z+eps): computed once here, reused ~tens of times in gather
      rec.w = 1.0f / (rec.z + EPSf);
      binned[slot] = rec;
      const int bv = g >> 16;
      const float* fp = feats + ((size_t)bv * Cc << 16) + n;
#pragma unroll
      for (int cgi = 0; cgi < 4; cgi++) {
        float4* dst = binnedF + (((size_t)cgi * NREC + slot) << 2);
#pragma unroll
        for (int i = 0; i < 4; i++) {
          const int c0 = cgi * 16 + 4 * i;
          float4 v;
          v.x = fp[(size_t)(c0 + 0) << 16];
          v.y = fp[(size_t)(c0 + 1) << 16];
          v.z = fp[(size_t)(c0 + 2) << 16];
          v.w = fp[(size_t)(c0 + 3) << 16];
          dst[i] = v;
        }
      }
    } else {
      rec.w = __int_as_float(n);
      binned[slot] = rec;
    }
  }
}

// ---------------- K4: gather — 16 ch/thread, planar slices, XCD swizzle,
//                  software-pipelined record loop (prefetch r+1) ----------
template <bool FSTAGED>
__global__ __launch_bounds__(256) void gather_kernel(
    const float* __restrict__ feats,  // planar (B,V,C,N), used when !FSTAGED
    const unsigned int* __restrict__ offs, const unsigned int* __restrict__ curs,
    const float4* __restrict__ binned, const float4* __restrict__ binnedF,
    float* __restrict__ out) {
  // XCD-aware swizzle: grid = 8192 = 8 XCDs x 1024. Each XCD gets one
  // contiguous chunk of "orig" = one full bv image (4 cg x 256 rows).
  const int cpx = gridDim.x >> 3;
  const int orig = (blockIdx.x & 7) * cpx + (blockIdx.x >> 3);
  const int bv = orig >> 10;
  const int cg = (orig >> 8) & 3;   // channel group: channels [cg*16, cg*16+16)
  const int vrow = orig & 255;
  const int u = threadIdx.x;

  float acc[16];
#pragma unroll
  for (int c = 0; c < 16; c++) acc[c] = 0.f;
  float wsum = 0.f, wz = 0.f;

  const float uf = (float)u, vf = (float)vrow;
  const int by_lo = max(0, vrow - 2), by_hi = min(Hd - 1, vrow + 2);
  const int bx_lo = max(0, u - 2), bx_hi = min(Wd - 1, u + 2);

  const float4* plane = binnedF + (((size_t)cg * NREC) << 2);

  for (int by = by_lo; by <= by_hi; by++) {
    const int rowb = (bv << 16) | (by << 8);
    const unsigned int s = offs[rowb + bx_lo];
    const unsigned int e = curs[rowb + bx_hi];
    if (FSTAGED) {
      if (s >= e) continue;
      // ---- software pipeline: stage 0 loads for record s ----
      float4 rec = binned[s];
      const float4* fs0 = plane + ((size_t)s << 2);
      float4 f0 = fs0[0], f1 = fs0[1], f2 = fs0[2], f3 = fs0[3];
      for (unsigned int r = s; r < e; r++) {
        // issue next record's loads before consuming current (guarded clamp
        // keeps addresses valid; redundant last-iter loads are L1 hits)
        const unsigned int rn = (r + 1 < e) ? r + 1 : r;
        const float4 rec_n = binned[rn];
        const float4* fsn = plane + ((size_t)rn << 2);
        const float4 g0 = fsn[0], g1 = fsn[1], g2 = fsn[2], g3 = fsn[3];

        const float ddx = uf - rec.x;
        const float ddy = vf - rec.y;
        const float dist = sqrtf(ddx * ddx + ddy * ddy + EPSf);
        // branchless: w==0 contributes nothing; rec.w == 1/(z+eps)
        const float w = fmaxf(0.0f, 1.0f - dist * 0.5f) * rec.w;
        wsum += w;
        wz += w * rec.z;
        acc[0]  += w * f0.x; acc[1]  += w * f0.y;
        acc[2]  += w * f0.z; acc[3]  += w * f0.w;
        acc[4]  += w * f1.x; acc[5]  += w * f1.y;
        acc[6]  += w * f1.z; acc[7]  += w * f1.w;
        acc[8]  += w * f2.x; acc[9]  += w * f2.y;
        acc[10] += w * f2.z; acc[11] += w * f2.w;
        acc[12] += w * f3.x; acc[13] += w * f3.y;
        acc[14] += w * f3.z; acc[15] += w * f3.w;

        rec = rec_n;
        f0 = g0; f1 = g1; f2 = g2; f3 = g3;
      }
    } else {
      for (unsigned int r = s; r < e; r++) {
        const float4 rec = binned[r];
        const float ddx = uf - rec.x;
        const float ddy = vf - rec.y;
        const float dist = sqrtf(ddx * ddx + ddy * ddy + EPSf);
        float w = 1.0f - dist * 0.5f;
        if (w > 0.f) {
          w *= 1.0f / (rec.z + EPSf);
          wsum += w;
          wz += w * rec.z;
          const int n = __float_as_int(rec.w);
          const float* fp = feats + ((size_t)bv * Cc << 16) + n;
#pragma unroll
          for (int c = 0; c < 16; c++)
            acc[c] += w * fp[(size_t)(cg * 16 + c) << 16];
        }
      }
    }
  }

  const float inv = 1.0f / (wsum + EPSf);
  const int dest = (vrow << 8) | u;
  float* ob = out + (((size_t)bv * 65) << 16) + ((size_t)(cg * 16) << 16) + dest;
#pragma unroll
  for (int c = 0; c < 16; c++) ob[(size_t)c << 16] = acc[c] * inv;
  if (cg == 0) {
    // depth plane (channel 64)
    out[(((size_t)bv * 65 + Cc) << 16) + dest] = wz * inv;
  }
}

// ---------------- fallback: round-1 atomic splat ----------------
__global__ __launch_bounds__(256) void splat_kernel(
    const float* __restrict__ feats, const float* __restrict__ depths,
    const float* __restrict__ Kmat, const float* __restrict__ srcinv,
    const float* __restrict__ dstRT, float* __restrict__ out,
    float* __restrict__ wsum) {
  const int bv = blockIdx.x >> 8;
  const int n = ((blockIdx.x & 255) << 8) | threadIdx.x;
  const int b = bv >> 2;

  __shared__ float T[16];
  if (threadIdx.x == 0) compute_T(Kmat, srcinv, dstRT, b, bv, T);
  __syncthreads();

  const float d = depths[(size_t)bv * Nn + n];
  const float gx = (float)(n & (Wd - 1));
  const float gy = (float)(n >> 8);
  const float p0 = (T[0] * gx + T[1] * gy + T[2]) * d + T[3];
  const float p1 = (T[4] * gx + T[5] * gy + T[6]) * d + T[7];
  const float z  = (T[8] * gx + T[9] * gy + T[10]) * d + T[11];
  const float ze = z + EPSf;
  const float x = p0 / ze, y = p1 / ze;
  const float zi = 1.0f / ze;
  const float px0 = rintf(x), py0 = rintf(y);
  const bool zok = (z > EPSf);

  float f[Cc];
  const float* fp = feats + (size_t)bv * Cc * Nn + n;
#pragma unroll
  for (int c = 0; c < Cc; c++) f[c] = fp[(size_t)c * Nn];

  float* outbv = out + (size_t)bv * 65 * Nn;
  float* wbv = wsum + (size_t)bv * Nn;
#pragma unroll
  for (int dy = -2; dy <= 2; dy++) {
#pragma unroll
    for (int dx = -2; dx <= 2; dx++) {
      const float px = px0 + (float)dx;
      const float py = py0 + (float)dy;
      const float ddx = px - x, ddy = py - y;
      const float dist = sqrtf(ddx * ddx + ddy * ddy + EPSf);
      float w = fmaxf(0.0f, 1.0f - dist * 0.5f);
      const bool valid = zok && (px >= 0.0f) && (px < (float)Wd) &&
                         (py >= 0.0f) && (py < (float)Hd);
      w = valid ? w * zi : 0.0f;
      if (w > 0.0f) {
        const int idx = (int)py * Wd + (int)px;
        atomicAdd(wbv + idx, w);
        atomicAdd(outbv + (size_t)Cc * Nn + idx, w * z);
#pragma unroll
        for (int c = 0; c < Cc; c++)
          atomicAdd(outbv + (size_t)c * Nn + idx, w * f[c]);
      }
    }
  }
}

__global__ __launch_bounds__(256) void norm_kernel(float* __restrict__ out,
                                                   const float* __restrict__ wsum) {
  const int t = blockIdx.x * 256 + threadIdx.x;
  const int n = t & 0xFFFF;
  const int bvc = t >> 16;
  const int bv = bvc / 65;
  const float wv = wsum[(size_t)bv * Nn + n];
  out[t] = out[t] / (wv + EPSf);
}

extern "C" void kernel_launch(void* const* d_in, const int* in_sizes, int n_in,
                              void* d_out, int out_size, void* d_ws, size_t ws_size,
                              hipStream_t stream) {
  const float* feats  = (const float*)d_in[0];
  const float* depths = (const float*)d_in[1];
  const float* Kmat   = (const float*)d_in[2];
  const float* srcinv = (const float*)d_in[4];
  const float* dstRT  = (const float*)d_in[5];
  float* out = (float*)d_out;
  char* ws = (char*)d_ws;

  if (ws_size >= NEED_MID) {
    unsigned int* counts = (unsigned int*)(ws + OFF_COUNT);
    unsigned int* offs   = (unsigned int*)(ws + OFF_OFFS);
    unsigned int* curs   = (unsigned int*)(ws + OFF_CURS);
    unsigned int* rowsum = (unsigned int*)(ws + OFF_ROWSUM);
    unsigned int* rowbase= (unsigned int*)(ws + OFF_ROWBASE);
    float4* stage1 = (float4*)(ws + OFF_STAGE1);
    float4* binned = (float4*)(ws + OFF_BINNED);
    float4* binnedF= (float4*)(ws + OFF_FT);

    hipMemsetAsync(counts, 0, (size_t)BVn * Nn * sizeof(unsigned int), stream);

    const bool staged = (ws_size >= NEED_FULL);

    project_count_kernel<<<dim3(BVn * (Nn / 256)), dim3(256), 0, stream>>>(
        depths, Kmat, srcinv, dstRT, counts, stage1);
    row_sum_kernel<<<dim3(512), dim3(256), 0, stream>>>(counts, rowsum);
    scan_rows_kernel<<<dim3(1), dim3(256), 0, stream>>>(rowsum, rowbase);
    bin_offsets_kernel<<<dim3(512), dim3(256), 0, stream>>>(counts, rowbase, offs, curs);

    if (staged) {
      fill_kernel<true><<<dim3(BVn * Nn / 256), dim3(256), 0, stream>>>(
          feats, stage1, curs, binned, binnedF);
      gather_kernel<true><<<dim3(BVn * 4 * Hd), dim3(256), 0, stream>>>(
          feats, offs, curs, binned, binnedF, out);
    } else {
      fill_kernel<false><<<dim3(BVn * Nn / 256), dim3(256), 0, stream>>>(
          feats, stage1, curs, binned, binnedF);
      gather_kernel<false><<<dim3(BVn * 4 * Hd), dim3(256), 0, stream>>>(
          feats, offs, curs, binned, binnedF, out);
    }
  } else {
    // atomic fallback (round-1 path)
    float* wsum = (float*)ws;  // (BV,N) = 2 MiB
    hipMemsetAsync(out, 0, (size_t)out_size * sizeof(float), stream);
    hipMemsetAsync(wsum, 0, (size_t)BVn * Nn * sizeof(float), stream);
    splat_kernel<<<dim3(BVn * (Nn / 256)), dim3(256), 0, stream>>>(
        feats, depths, Kmat, srcinv, dstRT, out, wsum);
    norm_kernel<<<dim3(BVn * 65 * Nn / 256), dim3(256), 0, stream>>>(out, wsum);
  }
}

// Round 15
// 662.676 us; speedup vs baseline: 1.0640x; 1.0640x over previous
//
#include <hip/hip_runtime.h>

#define Wd 256
#define Hd 256
#define Nn 65536   // H*W
#define Cc 64
#define Vv 4
#define Bb 2
#define BVn 8
#define NREC ((size_t)BVn * Nn)   // 524288 = 2^19
#define EPSf 1e-8f

// ---- workspace layout (bytes) ----
#define OFF_COUNT   ((size_t)0)            // u32[524288]  2 MiB
#define OFF_OFFS    ((size_t)2  << 20)     // u32[524288]  2 MiB
#define OFF_CURS    ((size_t)4  << 20)     // u32[524288]  2 MiB
#define OFF_ROWSUM  ((size_t)6  << 20)     // u32[2048]
#define OFF_ROWBASE (((size_t)6 << 20) + 65536)
#define OFF_STAGE1  ((size_t)8  << 20)     // float4[524288] 8 MiB
#define OFF_BINNED  ((size_t)16 << 20)     // float4[524288] 8 MiB
#define OFF_FT      ((size_t)24 << 20)     // binnedF planar: 4 x [524288 x 64B] = 128 MiB
#define FT_BYTES    ((size_t)BVn * Nn * Cc * 4)
#define NEED_FULL   (OFF_FT + FT_BYTES)
#define NEED_MID    OFF_FT

// ---------------- small matrix helpers ----------------
__device__ inline void mat4_mul(const float* A, const float* B, float* C) {
#pragma unroll
  for (int i = 0; i < 4; i++)
#pragma unroll
    for (int j = 0; j < 4; j++) {
      float s = 0.f;
#pragma unroll
      for (int k = 0; k < 4; k++) s += A[i * 4 + k] * B[k * 4 + j];
      C[i * 4 + j] = s;
    }
}

__device__ inline void mat4_inv(const float* m, float* invOut) {
  float inv[16];
  inv[0] = m[5]*m[10]*m[15] - m[5]*m[11]*m[14] - m[9]*m[6]*m[15] +
           m[9]*m[7]*m[14] + m[13]*m[6]*m[11] - m[13]*m[7]*m[10];
  inv[4] = -m[4]*m[10]*m[15] + m[4]*m[11]*m[14] + m[8]*m[6]*m[15] -
           m[8]*m[7]*m[14] - m[12]*m[6]*m[11] + m[12]*m[7]*m[10];
  inv[8] = m[4]*m[9]*m[15] - m[4]*m[11]*m[13] - m[8]*m[5]*m[15] +
           m[8]*m[7]*m[13] + m[12]*m[5]*m[11] - m[12]*m[7]*m[9];
  inv[12] = -m[4]*m[9]*m[14] + m[4]*m[10]*m[13] + m[8]*m[5]*m[14] -
            m[8]*m[6]*m[13] - m[12]*m[5]*m[10] + m[12]*m[6]*m[9];
  inv[1] = -m[1]*m[10]*m[15] + m[1]*m[11]*m[14] + m[9]*m[2]*m[15] -
           m[9]*m[3]*m[14] - m[13]*m[2]*m[11] + m[13]*m[3]*m[10];
  inv[5] = m[0]*m[10]*m[15] - m[0]*m[11]*m[14] - m[8]*m[2]*m[15] +
           m[8]*m[3]*m[14] + m[12]*m[2]*m[11] - m[12]*m[3]*m[10];
  inv[9] = -m[0]*m[9]*m[15] + m[0]*m[11]*m[13] + m[8]*m[1]*m[15] -
           m[8]*m[3]*m[13] - m[12]*m[1]*m[11] + m[12]*m[3]*m[9];
  inv[13] = m[0]*m[9]*m[14] - m[0]*m[10]*m[13] - m[8]*m[1]*m[14] +
            m[8]*m[2]*m[13] + m[12]*m[1]*m[10] - m[12]*m[2]*m[9];
  inv[2] = m[1]*m[6]*m[15] - m[1]*m[7]*m[14] - m[5]*m[2]*m[15] +
           m[5]*m[3]*m[14] + m[13]*m[2]*m[7] - m[13]*m[3]*m[6];
  inv[6] = -m[0]*m[6]*m[15] + m[0]*m[7]*m[14] + m[4]*m[2]*m[15] -
           m[4]*m[3]*m[14] - m[12]*m[2]*m[7] + m[12]*m[3]*m[6];
  inv[10] = m[0]*m[5]*m[15] - m[0]*m[7]*m[13] - m[4]*m[1]*m[15] +
            m[4]*m[3]*m[13] + m[12]*m[1]*m[7] - m[12]*m[3]*m[5];
  inv[14] = -m[0]*m[5]*m[14] + m[0]*m[6]*m[13] + m[4]*m[1]*m[14] -
            m[4]*m[2]*m[13] - m[12]*m[1]*m[6] + m[12]*m[2]*m[5];
  inv[3] = -m[1]*m[6]*m[11] + m[1]*m[7]*m[10] + m[5]*m[2]*m[11] -
           m[5]*m[3]*m[10] - m[9]*m[2]*m[7] + m[9]*m[3]*m[6];
  inv[7] = m[0]*m[6]*m[11] - m[0]*m[7]*m[10] - m[4]*m[2]*m[11] +
           m[4]*m[3]*m[10] + m[8]*m[2]*m[7] - m[8]*m[3]*m[6];
  inv[11] = -m[0]*m[5]*m[11] + m[0]*m[7]*m[9] + m[4]*m[1]*m[11] -
            m[4]*m[3]*m[9] - m[8]*m[1]*m[7] + m[8]*m[3]*m[5];
  inv[15] = m[0]*m[5]*m[10] - m[0]*m[6]*m[9] - m[4]*m[1]*m[10] +
            m[4]*m[2]*m[9] + m[8]*m[1]*m[6] - m[8]*m[2]*m[5];
  float det = m[0]*inv[0] + m[1]*inv[4] + m[2]*inv[8] + m[3]*inv[12];
  det = 1.0f / det;
#pragma unroll
  for (int i = 0; i < 16; i++) invOut[i] = inv[i] * det;
}

__device__ inline void compute_T(const float* Kmat, const float* srcinv,
                                 const float* dstRT, int b, int bv, float* T) {
  float Kinv[16], M1[16], M2[16];
  mat4_inv(Kmat + b * 16, Kinv);
  mat4_mul(srcinv + bv * 16, Kinv, M1);
  mat4_mul(dstRT + b * 16, M1, M2);
  mat4_mul(Kmat + b * 16, M2, T);
}

// ---------------- K1: project, count, stage ----------------
__global__ __launch_bounds__(256) void project_count_kernel(
    const float* __restrict__ depths, const float* __restrict__ Kmat,
    const float* __restrict__ srcinv, const float* __restrict__ dstRT,
    unsigned int* __restrict__ counts, float4* __restrict__ stage1) {
  const int bv = blockIdx.x >> 8;
  const int n = ((blockIdx.x & 255) << 8) | threadIdx.x;
  const int b = bv >> 2;

  __shared__ float T[16];
  if (threadIdx.x == 0) compute_T(Kmat, srcinv, dstRT, b, bv, T);
  __syncthreads();

  const float d = depths[(size_t)bv * Nn + n];
  const float gx = (float)(n & (Wd - 1));
  const float gy = (float)(n >> 8);

  const float p0 = (T[0] * gx + T[1] * gy + T[2]) * d + T[3];
  const float p1 = (T[4] * gx + T[5] * gy + T[6]) * d + T[7];
  const float z  = (T[8] * gx + T[9] * gy + T[10]) * d + T[11];

  const float ze = z + EPSf;
  const float x = p0 / ze;
  const float y = p1 / ze;
  const float px0 = rintf(x);
  const float py0 = rintf(y);

  int bin = -1;
  if (z > EPSf && px0 >= -2.0f && px0 <= (float)(Wd + 1) &&
      py0 >= -2.0f && py0 <= (float)(Hd + 1)) {
    const int bx = min(max((int)px0, 0), Wd - 1);
    const int by = min(max((int)py0, 0), Hd - 1);
    bin = (bv << 16) | (by << 8) | bx;
    atomicAdd(&counts[bin], 1u);
  }
  float4 rec;
  rec.x = x; rec.y = y; rec.z = z; rec.w = __int_as_float(bin);
  stage1[(size_t)bv * Nn + n] = rec;
}

// ---------------- K2a: per-row sums — one wave per row ----------------
__global__ __launch_bounds__(256) void row_sum_kernel(
    const unsigned int* __restrict__ counts, unsigned int* __restrict__ rowsum) {
  const int wid = threadIdx.x >> 6;
  const int lane = threadIdx.x & 63;
  const int r = blockIdx.x * 4 + wid;  // 512 blocks x 4 waves = 2048 rows
  const uint4 c = reinterpret_cast<const uint4*>(counts + (size_t)r * 256)[lane];
  unsigned int s = c.x + c.y + c.z + c.w;
#pragma unroll
  for (int off = 32; off > 0; off >>= 1) s += __shfl_down(s, off, 64);
  if (lane == 0) rowsum[r] = s;
}

// ---------------- K2b: exclusive scan of 2048 row sums (one block) --------
__global__ __launch_bounds__(256) void scan_rows_kernel(
    const unsigned int* __restrict__ rowsum, unsigned int* __restrict__ rowbase) {
  __shared__ unsigned int part[256];
  const int t = threadIdx.x;
  unsigned int loc[8];
  unsigned int run = 0;
#pragma unroll
  for (int i = 0; i < 8; i++) {
    loc[i] = run;
    run += rowsum[t * 8 + i];
  }
  part[t] = run;
  __syncthreads();
  for (int off = 1; off < 256; off <<= 1) {
    unsigned int x = part[t];
    unsigned int y = (t >= off) ? part[t - off] : 0u;
    __syncthreads();
    part[t] = x + y;
    __syncthreads();
  }
  const unsigned int base = (t == 0) ? 0u : part[t - 1];
#pragma unroll
  for (int i = 0; i < 8; i++) rowbase[t * 8 + i] = base + loc[i];
}

// ---------------- K2c: per-bin offsets + cursors — one wave per row -------
__global__ __launch_bounds__(256) void bin_offsets_kernel(
    const unsigned int* __restrict__ counts, const unsigned int* __restrict__ rowbase,
    unsigned int* __restrict__ offs, unsigned int* __restrict__ curs) {
  const int wid = threadIdx.x >> 6;
  const int lane = threadIdx.x & 63;
  const int r = blockIdx.x * 4 + wid;  // 512 blocks x 4 waves = 2048 rows
  const uint4 c = reinterpret_cast<const uint4*>(counts + (size_t)r * 256)[lane];
  const unsigned int t0 = c.x;
  const unsigned int t1 = t0 + c.y;
  const unsigned int t2 = t1 + c.z;
  const unsigned int t3 = t2 + c.w;  // quad inclusive total
  unsigned int inc = t3;
#pragma unroll
  for (int off = 1; off < 64; off <<= 1) {
    const unsigned int v = __shfl_up(inc, off, 64);
    if (lane >= off) inc += v;
  }
  const unsigned int base = rowbase[r] + inc - t3;  // exclusive prefix
  uint4 o;
  o.x = base;
  o.y = base + t0;
  o.z = base + t1;
  o.w = base + t2;
  reinterpret_cast<uint4*>(offs + (size_t)r * 256)[lane] = o;
  reinterpret_cast<uint4*>(curs + (size_t)r * 256)[lane] = o;
}

// ---------------- K3: fill binned records (+ planar feature slices) -------
// binnedF layout: 4 planes of [NREC][16 floats]; plane cg holds channels
// [cg*16, cg*16+16) of every record. Gather block cg streams plane cg
// densely (consecutive records are adjacent 64B) -> no cache-line split.
template <bool FSTAGED>
__global__ __launch_bounds__(256) void fill_kernel(
    const float* __restrict__ feats, const float4* __restrict__ stage1,
    unsigned int* __restrict__ curs, float4* __restrict__ binned,
    float4* __restrict__ binnedF) {
  const int g = blockIdx.x * 256 + threadIdx.x;  // 0..524287
  float4 rec = stage1[g];
  const int bin = __float_as_int(rec.w);
  if (bin >= 0) {
    const unsigned int slot = atomicAdd(&curs[bin], 1u);
    const int n = g & (Nn - 1);
    if (FSTAGED) {
      // rec.w = 1/(z+eps): computed once here, reused ~tens of times in gather
      rec.w = 1.0f / (rec.z + EPSf);
      binned[slot] = rec;
      const int bv = g >> 16;
      const float* fp = feats + ((size_t)bv * Cc << 16) + n;
#pragma unroll
      for (int cgi = 0; cgi < 4; cgi++) {
        float4* dst = binnedF + (((size_t)cgi * NREC + slot) << 2);
#pragma unroll
        for (int i = 0; i < 4; i++) {
          const int c0 = cgi * 16 + 4 * i;
          float4 v;
          v.x = fp[(size_t)(c0 + 0) << 16];
          v.y = fp[(size_t)(c0 + 1) << 16];
          v.z = fp[(size_t)(c0 + 2) << 16];
          v.w = fp[(size_t)(c0 + 3) << 16];
          dst[i] = v;
        }
      }
    } else {
      rec.w = __int_as_float(n);
      binned[slot] = rec;
    }
  }
}

// ---------------- gather helper: one record's contribution ----------------
__device__ inline void gather_one(const float4 rec, const float4 f0,
                                  const float4 f1, const float4 f2,
                                  const float4 f3, const float uf,
                                  const float vf, float* acc, float& wsum,
                                  float& wz) {
  const float ddx = uf - rec.x;
  const float ddy = vf - rec.y;
  const float dist = sqrtf(ddx * ddx + ddy * ddy + EPSf);
  // branchless: w==0 contributes nothing; rec.w == 1/(z+eps)
  const float w = fmaxf(0.0f, 1.0f - dist * 0.5f) * rec.w;
  wsum += w;
  wz += w * rec.z;
  acc[0]  += w * f0.x; acc[1]  += w * f0.y;
  acc[2]  += w * f0.z; acc[3]  += w * f0.w;
  acc[4]  += w * f1.x; acc[5]  += w * f1.y;
  acc[6]  += w * f1.z; acc[7]  += w * f1.w;
  acc[8]  += w * f2.x; acc[9]  += w * f2.y;
  acc[10] += w * f2.z; acc[11] += w * f2.w;
  acc[12] += w * f3.x; acc[13] += w * f3.y;
  acc[14] += w * f3.z; acc[15] += w * f3.w;
}

// ---------------- K4: gather — 16 ch/thread, planar slices, XCD swizzle,
//                  2-way unrolled record loop (independent records) -------
template <bool FSTAGED>
__global__ __launch_bounds__(256) void gather_kernel(
    const float* __restrict__ feats,  // planar (B,V,C,N), used when !FSTAGED
    const unsigned int* __restrict__ offs, const unsigned int* __restrict__ curs,
    const float4* __restrict__ binned, const float4* __restrict__ binnedF,
    float* __restrict__ out) {
  // XCD-aware swizzle: grid = 8192 = 8 XCDs x 1024. Each XCD gets one
  // contiguous chunk of "orig" = one full bv image (4 cg x 256 rows).
  const int cpx = gridDim.x >> 3;
  const int orig = (blockIdx.x & 7) * cpx + (blockIdx.x >> 3);
  const int bv = orig >> 10;
  const int cg = (orig >> 8) & 3;   // channel group: channels [cg*16, cg*16+16)
  const int vrow = orig & 255;
  const int u = threadIdx.x;

  float acc[16];
#pragma unroll
  for (int c = 0; c < 16; c++) acc[c] = 0.f;
  float wsum = 0.f, wz = 0.f;

  const float uf = (float)u, vf = (float)vrow;
  const int by_lo = max(0, vrow - 2), by_hi = min(Hd - 1, vrow + 2);
  const int bx_lo = max(0, u - 2), bx_hi = min(Wd - 1, u + 2);

  const float4* plane = binnedF + (((size_t)cg * NREC) << 2);

  for (int by = by_lo; by <= by_hi; by++) {
    const int rowb = (bv << 16) | (by << 8);
    const unsigned int s = offs[rowb + bx_lo];
    const unsigned int e = curs[rowb + bx_hi];
    if (FSTAGED) {
      unsigned int r = s;
      // 2-way unroll: two INDEPENDENT records per iteration -> both load
      // chains issue before either is consumed (MLP=2, can't be sunk).
      for (; r + 1 < e; r += 2) {
        const float4 recA = binned[r];
        const float4 recB = binned[r + 1];
        const float4* fsA = plane + ((size_t)r << 2);
        const float4* fsB = plane + ((size_t)(r + 1) << 2);
        const float4 a0 = fsA[0], a1 = fsA[1], a2 = fsA[2], a3 = fsA[3];
        const float4 b0 = fsB[0], b1 = fsB[1], b2 = fsB[2], b3 = fsB[3];
        gather_one(recA, a0, a1, a2, a3, uf, vf, acc, wsum, wz);
        gather_one(recB, b0, b1, b2, b3, uf, vf, acc, wsum, wz);
      }
      if (r < e) {
        const float4 recA = binned[r];
        const float4* fsA = plane + ((size_t)r << 2);
        const float4 a0 = fsA[0], a1 = fsA[1], a2 = fsA[2], a3 = fsA[3];
        gather_one(recA, a0, a1, a2, a3, uf, vf, acc, wsum, wz);
      }
    } else {
      for (unsigned int r = s; r < e; r++) {
        const float4 rec = binned[r];
        const float ddx = uf - rec.x;
        const float ddy = vf - rec.y;
        const float dist = sqrtf(ddx * ddx + ddy * ddy + EPSf);
        float w = 1.0f - dist * 0.5f;
        if (w > 0.f) {
          w *= 1.0f / (rec.z + EPSf);
          wsum += w;
          wz += w * rec.z;
          const int n = __float_as_int(rec.w);
          const float* fp = feats + ((size_t)bv * Cc << 16) + n;
#pragma unroll
          for (int c = 0; c < 16; c++)
            acc[c] += w * fp[(size_t)(cg * 16 + c) << 16];
        }
      }
    }
  }

  const float inv = 1.0f / (wsum + EPSf);
  const int dest = (vrow << 8) | u;
  float* ob = out + (((size_t)bv * 65) << 16) + ((size_t)(cg * 16) << 16) + dest;
#pragma unroll
  for (int c = 0; c < 16; c++) ob[(size_t)c << 16] = acc[c] * inv;
  if (cg == 0) {
    // depth plane (channel 64)
    out[(((size_t)bv * 65 + Cc) << 16) + dest] = wz * inv;
  }
}

// ---------------- fallback: round-1 atomic splat ----------------
__global__ __launch_bounds__(256) void splat_kernel(
    const float* __restrict__ feats, const float* __restrict__ depths,
    const float* __restrict__ Kmat, const float* __restrict__ srcinv,
    const float* __restrict__ dstRT, float* __restrict__ out,
    float* __restrict__ wsum) {
  const int bv = blockIdx.x >> 8;
  const int n = ((blockIdx.x & 255) << 8) | threadIdx.x;
  const int b = bv >> 2;

  __shared__ float T[16];
  if (threadIdx.x == 0) compute_T(Kmat, srcinv, dstRT, b, bv, T);
  __syncthreads();

  const float d = depths[(size_t)bv * Nn + n];
  const float gx = (float)(n & (Wd - 1));
  const float gy = (float)(n >> 8);
  const float p0 = (T[0] * gx + T[1] * gy + T[2]) * d + T[3];
  const float p1 = (T[4] * gx + T[5] * gy + T[6]) * d + T[7];
  const float z  = (T[8] * gx + T[9] * gy + T[10]) * d + T[11];
  const float ze = z + EPSf;
  const float x = p0 / ze, y = p1 / ze;
  const float zi = 1.0f / ze;
  const float px0 = rintf(x), py0 = rintf(y);
  const bool zok = (z > EPSf);

  float f[Cc];
  const float* fp = feats + (size_t)bv * Cc * Nn + n;
#pragma unroll
  for (int c = 0; c < Cc; c++) f[c] = fp[(size_t)c * Nn];

  float* outbv = out + (size_t)bv * 65 * Nn;
  float* wbv = wsum + (size_t)bv * Nn;
#pragma unroll
  for (int dy = -2; dy <= 2; dy++) {
#pragma unroll
    for (int dx = -2; dx <= 2; dx++) {
      const float px = px0 + (float)dx;
      const float py = py0 + (float)dy;
      const float ddx = px - x, ddy = py - y;
      const float dist = sqrtf(ddx * ddx + ddy * ddy + EPSf);
      float w = fmaxf(0.0f, 1.0f - dist * 0.5f);
      const bool valid = zok && (px >= 0.0f) && (px < (float)Wd) &&
                         (py >= 0.0f) && (py < (float)Hd);
      w = valid ? w * zi : 0.0f;
      if (w > 0.0f) {
        const int idx = (int)py * Wd + (int)px;
        atomicAdd(wbv + idx, w);
        atomicAdd(outbv + (size_t)Cc * Nn + idx, w * z);
#pragma unroll
        for (int c = 0; c < Cc; c++)
          atomicAdd(outbv + (size_t)c * Nn + idx, w * f[c]);
      }
    }
  }
}

__global__ __launch_bounds__(256) void norm_kernel(float* __restrict__ out,
                                                   const float* __restrict__ wsum) {
  const int t = blockIdx.x * 256 + threadIdx.x;
  const int n = t & 0xFFFF;
  const int bvc = t >> 16;
  const int bv = bvc / 65;
  const float wv = wsum[(size_t)bv * Nn + n];
  out[t] = out[t] / (wv + EPSf);
}

extern "C" void kernel_launch(void* const* d_in, const int* in_sizes, int n_in,
                              void* d_out, int out_size, void* d_ws, size_t ws_size,
                              hipStream_t stream) {
  const float* feats  = (const float*)d_in[0];
  const float* depths = (const float*)d_in[1];
  const float* Kmat   = (const float*)d_in[2];
  const float* srcinv = (const float*)d_in[4];
  const float* dstRT  = (const float*)d_in[5];
  float* out = (float*)d_out;
  char* ws = (char*)d_ws;

  if (ws_size >= NEED_MID) {
    unsigned int* counts = (unsigned int*)(ws + OFF_COUNT);
    unsigned int* offs   = (unsigned int*)(ws + OFF_OFFS);
    unsigned int* curs   = (unsigned int*)(ws + OFF_CURS);
    unsigned int* rowsum = (unsigned int*)(ws + OFF_ROWSUM);
    unsigned int* rowbase= (unsigned int*)(ws + OFF_ROWBASE);
    float4* stage1 = (float4*)(ws + OFF_STAGE1);
    float4* binned = (float4*)(ws + OFF_BINNED);
    float4* binnedF= (float4*)(ws + OFF_FT);

    hipMemsetAsync(counts, 0, (size_t)BVn * Nn * sizeof(unsigned int), stream);

    const bool staged = (ws_size >= NEED_FULL);

    project_count_kernel<<<dim3(BVn * (Nn / 256)), dim3(256), 0, stream>>>(
        depths, Kmat, srcinv, dstRT, counts, stage1);
    row_sum_kernel<<<dim3(512), dim3(256), 0, stream>>>(counts, rowsum);
    scan_rows_kernel<<<dim3(1), dim3(256), 0, stream>>>(rowsum, rowbase);
    bin_offsets_kernel<<<dim3(512), dim3(256), 0, stream>>>(counts, rowbase, offs, curs);

    if (staged) {
      fill_kernel<true><<<dim3(BVn * Nn / 256), dim3(256), 0, stream>>>(
          feats, stage1, curs, binned, binnedF);
      gather_kernel<true><<<dim3(BVn * 4 * Hd), dim3(256), 0, stream>>>(
          feats, offs, curs, binned, binnedF, out);
    } else {
      fill_kernel<false><<<dim3(BVn * Nn / 256), dim3(256), 0, stream>>>(
          feats, stage1, curs, binned, binnedF);
      gather_kernel<false><<<dim3(BVn * 4 * Hd), dim3(256), 0, stream>>>(
          feats, offs, curs, binned, binnedF, out);
    }
  } else {
    // atomic fallback (round-1 path)
    float* wsum = (float*)ws;  // (BV,N) = 2 MiB
    hipMemsetAsync(out, 0, (size_t)out_size * sizeof(float), stream);
    hipMemsetAsync(wsum, 0, (size_t)BVn * Nn * sizeof(float), stream);
    splat_kernel<<<dim3(BVn * (Nn / 256)), dim3(256), 0, stream>>>(
        feats, depths, Kmat, srcinv, dstRT, out, wsum);
    norm_kernel<<<dim3(BVn * 65 * Nn / 256), dim3(256), 0, stream>>>(out, wsum);
  }
}

// Round 17
// 625.075 us; speedup vs baseline: 1.1280x; 1.0602x over previous
//
#include <hip/hip_runtime.h>

#define Wd 256
#define Hd 256
#define Nn 65536   // H*W
#define Cc 64
#define Vv 4
#define Bb 2
#define BVn 8
#define NREC ((size_t)BVn * Nn)   // 524288 = 2^19
#define EPSf 1e-8f

// ---- workspace layout (bytes) ----
#define OFF_COUNT   ((size_t)0)            // u32[524288]  2 MiB
#define OFF_OFFS    ((size_t)2  << 20)     // u32[524288]  2 MiB
#define OFF_CURS    ((size_t)4  << 20)     // u32[524288]  2 MiB
#define OFF_ROWSUM  ((size_t)6  << 20)     // u32[2048]
#define OFF_ROWBASE (((size_t)6 << 20) + 65536)
#define OFF_STAGE1  ((size_t)8  << 20)     // float4[524288] 8 MiB
#define OFF_BINNED  ((size_t)16 << 20)     // float4[524288] 8 MiB
#define OFF_FT      ((size_t)24 << 20)     // binnedF planar: 4 x [524288 x 64B] = 128 MiB
#define FT_BYTES    ((size_t)BVn * Nn * Cc * 4)
#define NEED_FULL   (OFF_FT + FT_BYTES)
#define NEED_MID    OFF_FT

// ---------------- small matrix helpers ----------------
__device__ inline void mat4_mul(const float* A, const float* B, float* C) {
#pragma unroll
  for (int i = 0; i < 4; i++)
#pragma unroll
    for (int j = 0; j < 4; j++) {
      float s = 0.f;
#pragma unroll
      for (int k = 0; k < 4; k++) s += A[i * 4 + k] * B[k * 4 + j];
      C[i * 4 + j] = s;
    }
}

__device__ inline void mat4_inv(const float* m, float* invOut) {
  float inv[16];
  inv[0] = m[5]*m[10]*m[15] - m[5]*m[11]*m[14] - m[9]*m[6]*m[15] +
           m[9]*m[7]*m[14] + m[13]*m[6]*m[11] - m[13]*m[7]*m[10];
  inv[4] = -m[4]*m[10]*m[15] + m[4]*m[11]*m[14] + m[8]*m[6]*m[15] -
           m[8]*m[7]*m[14] - m[12]*m[6]*m[11] + m[12]*m[7]*m[10];
  inv[8] = m[4]*m[9]*m[15] - m[4]*m[11]*m[13] - m[8]*m[5]*m[15] +
           m[8]*m[7]*m[13] + m[12]*m[5]*m[11] - m[12]*m[7]*m[9];
  inv[12] = -m[4]*m[9]*m[14] + m[4]*m[10]*m[13] + m[8]*m[5]*m[14] -
            m[8]*m[6]*m[13] - m[12]*m[5]*m[10] + m[12]*m[6]*m[9];
  inv[1] = -m[1]*m[10]*m[15] + m[1]*m[11]*m[14] + m[9]*m[2]*m[15] -
           m[9]*m[3]*m[14] - m[13]*m[2]*m[11] + m[13]*m[3]*m[10];
  inv[5] = m[0]*m[10]*m[15] - m[0]*m[11]*m[14] - m[8]*m[2]*m[15] +
           m[8]*m[3]*m[14] + m[12]*m[2]*m[11] - m[12]*m[3]*m[10];
  inv[9] = -m[0]*m[9]*m[15] + m[0]*m[11]*m[13] + m[8]*m[1]*m[15] -
           m[8]*m[3]*m[13] - m[12]*m[1]*m[11] + m[12]*m[3]*m[9];
  inv[13] = m[0]*m[9]*m[14] - m[0]*m[10]*m[13] - m[8]*m[1]*m[14] +
            m[8]*m[2]*m[13] + m[12]*m[1]*m[10] - m[12]*m[2]*m[9];
  inv[2] = m[1]*m[6]*m[15] - m[1]*m[7]*m[14] - m[5]*m[2]*m[15] +
           m[5]*m[3]*m[14] + m[13]*m[2]*m[7] - m[13]*m[3]*m[6];
  inv[6] = -m[0]*m[6]*m[15] + m[0]*m[7]*m[14] + m[4]*m[2]*m[15] -
           m[4]*m[3]*m[14] - m[12]*m[2]*m[7] + m[12]*m[3]*m[6];
  inv[10] = m[0]*m[5]*m[15] - m[0]*m[7]*m[13] - m[4]*m[1]*m[15] +
            m[4]*m[3]*m[13] + m[12]*m[1]*m[7] - m[12]*m[3]*m[5];
  inv[14] = -m[0]*m[5]*m[14] + m[0]*m[6]*m[13] + m[4]*m[1]*m[14] -
            m[4]*m[2]*m[13] - m[12]*m[1]*m[6] + m[12]*m[2]*m[5];
  inv[3] = -m[1]*m[6]*m[11] + m[1]*m[7]*m[10] + m[5]*m[2]*m[11] -
           m[5]*m[3]*m[10] - m[9]*m[2]*m[7] + m[9]*m[3]*m[6];
  inv[7] = m[0]*m[6]*m[11] - m[0]*m[7]*m[10] - m[4]*m[2]*m[11] +
           m[4]*m[3]*m[10] + m[8]*m[2]*m[7] - m[8]*m[3]*m[6];
  inv[11] = -m[0]*m[5]*m[11] + m[0]*m[7]*m[9] + m[4]*m[1]*m[11] -
            m[4]*m[3]*m[9] - m[8]*m[1]*m[7] + m[8]*m[3]*m[5];
  inv[15] = m[0]*m[5]*m[10] - m[0]*m[6]*m[9] - m[4]*m[1]*m[10] +
            m[4]*m[2]*m[9] + m[8]*m[1]*m[6] - m[8]*m[2]*m[5];
  float det = m[0]*inv[0] + m[1]*inv[4] + m[2]*inv[8] + m[3]*inv[12];
  det = 1.0f / det;
#pragma unroll
  for (int i = 0; i < 16; i++) invOut[i] = inv[i] * det;
}

__device__ inline void compute_T(const float* Kmat, const float* srcinv,
                                 const float* dstRT, int b, int bv, float* T) {
  float Kinv[16], M1[16], M2[16];
  mat4_inv(Kmat + b * 16, Kinv);
  mat4_mul(srcinv + bv * 16, Kinv, M1);
  mat4_mul(dstRT + b * 16, M1, M2);
  mat4_mul(Kmat + b * 16, M2, T);
}

// ---------------- K1: project, count, stage ----------------
__global__ __launch_bounds__(256) void project_count_kernel(
    const float* __restrict__ depths, const float* __restrict__ Kmat,
    const float* __restrict__ srcinv, const float* __restrict__ dstRT,
    unsigned int* __restrict__ counts, float4* __restrict__ stage1) {
  const int bv = blockIdx.x >> 8;
  const int n = ((blockIdx.x & 255) << 8) | threadIdx.x;
  const int b = bv >> 2;

  __shared__ float T[16];
  if (threadIdx.x == 0) compute_T(Kmat, srcinv, dstRT, b, bv, T);
  __syncthreads();

  const float d = depths[(size_t)bv * Nn + n];
  const float gx = (float)(n & (Wd - 1));
  const float gy = (float)(n >> 8);

  const float p0 = (T[0] * gx + T[1] * gy + T[2]) * d + T[3];
  const float p1 = (T[4] * gx + T[5] * gy + T[6]) * d + T[7];
  const float z  = (T[8] * gx + T[9] * gy + T[10]) * d + T[11];

  const float ze = z + EPSf;
  const float x = p0 / ze;
  const float y = p1 / ze;
  const float px0 = rintf(x);
  const float py0 = rintf(y);

  int bin = -1;
  if (z > EPSf && px0 >= -2.0f && px0 <= (float)(Wd + 1) &&
      py0 >= -2.0f && py0 <= (float)(Hd + 1)) {
    const int bx = min(max((int)px0, 0), Wd - 1);
    const int by = min(max((int)py0, 0), Hd - 1);
    bin = (bv << 16) | (by << 8) | bx;
    atomicAdd(&counts[bin], 1u);
  }
  float4 rec;
  rec.x = x; rec.y = y; rec.z = z; rec.w = __int_as_float(bin);
  stage1[(size_t)bv * Nn + n] = rec;
}

// ---------------- K2a: per-row sums — one wave per row ----------------
__global__ __launch_bounds__(256) void row_sum_kernel(
    const unsigned int* __restrict__ counts, unsigned int* __restrict__ rowsum) {
  const int wid = threadIdx.x >> 6;
  const int lane = threadIdx.x & 63;
  const int r = blockIdx.x * 4 + wid;  // 512 blocks x 4 waves = 2048 rows
  const uint4 c = reinterpret_cast<const uint4*>(counts + (size_t)r * 256)[lane];
  unsigned int s = c.x + c.y + c.z + c.w;
#pragma unroll
  for (int off = 32; off > 0; off >>= 1) s += __shfl_down(s, off, 64);
  if (lane == 0) rowsum[r] = s;
}

// ---------------- K2b: exclusive scan of 2048 row sums (one block) --------
__global__ __launch_bounds__(256) void scan_rows_kernel(
    const unsigned int* __restrict__ rowsum, unsigned int* __restrict__ rowbase) {
  __shared__ unsigned int part[256];
  const int t = threadIdx.x;
  unsigned int loc[8];
  unsigned int run = 0;
#pragma unroll
  for (int i = 0; i < 8; i++) {
    loc[i] = run;
    run += rowsum[t * 8 + i];
  }
  part[t] = run;
  __syncthreads();
  for (int off = 1; off < 256; off <<= 1) {
    unsigned int x = part[t];
    unsigned int y = (t >= off) ? part[t - off] : 0u;
    __syncthreads();
    part[t] = x + y;
    __syncthreads();
  }
  const unsigned int base = (t == 0) ? 0u : part[t - 1];
#pragma unroll
  for (int i = 0; i < 8; i++) rowbase[t * 8 + i] = base + loc[i];
}

// ---------------- K2c: per-bin offsets + cursors — one wave per row -------
__global__ __launch_bounds__(256) void bin_offsets_kernel(
    const unsigned int* __restrict__ counts, const unsigned int* __restrict__ rowbase,
    unsigned int* __restrict__ offs, unsigned int* __restrict__ curs) {
  const int wid = threadIdx.x >> 6;
  const int lane = threadIdx.x & 63;
  const int r = blockIdx.x * 4 + wid;  // 512 blocks x 4 waves = 2048 rows
  const uint4 c = reinterpret_cast<const uint4*>(counts + (size_t)r * 256)[lane];
  const unsigned int t0 = c.x;
  const unsigned int t1 = t0 + c.y;
  const unsigned int t2 = t1 + c.z;
  const unsigned int t3 = t2 + c.w;  // quad inclusive total
  unsigned int inc = t3;
#pragma unroll
  for (int off = 1; off < 64; off <<= 1) {
    const unsigned int v = __shfl_up(inc, off, 64);
    if (lane >= off) inc += v;
  }
  const unsigned int base = rowbase[r] + inc - t3;  // exclusive prefix
  uint4 o;
  o.x = base;
  o.y = base + t0;
  o.z = base + t1;
  o.w = base + t2;
  reinterpret_cast<uint4*>(offs + (size_t)r * 256)[lane] = o;
  reinterpret_cast<uint4*>(curs + (size_t)r * 256)[lane] = o;
}

// ---------------- K3: fill binned records (+ planar feature slices) -------
// binnedF layout: 4 planes of [NREC][16 floats]; plane cg holds channels
// [cg*16, cg*16+16) of every record. Gather block cg streams plane cg
// densely (consecutive records are adjacent 64B) -> no cache-line split.
template <bool FSTAGED>
__global__ __launch_bounds__(256) void fill_kernel(
    const float* __restrict__ feats, const float4* __restrict__ stage1,
    unsigned int* __restrict__ curs, float4* __restrict__ binned,
    float4* __restrict__ binnedF) {
  const int g = blockIdx.x * 256 + threadIdx.x;  // 0..524287
  float4 rec = stage1[g];
  const int bin = __float_as_int(rec.w);
  if (bin >= 0) {
    const unsigned int slot = atomicAdd(&curs[bin], 1u);
    const int n = g & (Nn - 1);
    if (FSTAGED) {
      // rec.w = 1/(z+eps): computed once here, reused ~tens of times in gather
      rec.w = 1.0f / (rec.z + EPSf);
      binned[slot] = rec;
      const int bv = g >> 16;
      const float* fp = feats + ((size_t)bv * Cc << 16) + n;
#pragma unroll
      for (int cgi = 0; cgi < 4; cgi++) {
        float4* dst = binnedF + (((size_t)cgi * NREC + slot) << 2);
#pragma unroll
        for (int i = 0; i < 4; i++) {
          const int c0 = cgi * 16 + 4 * i;
          float4 v;
          v.x = fp[(size_t)(c0 + 0) << 16];
          v.y = fp[(size_t)(c0 + 1) << 16];
          v.z = fp[(size_t)(c0 + 2) << 16];
          v.w = fp[(size_t)(c0 + 3) << 16];
          dst[i] = v;
        }
      }
    } else {
      rec.w = __int_as_float(n);
      binned[slot] = rec;
    }
  }
}

// ---------------- gather helper: one record's contribution ----------------
__device__ inline void gather_one(const float4 rec, const float4 f0,
                                  const float4 f1, const float4 f2,
                                  const float4 f3, const float uf,
                                  const float vf, float* acc, float& wsum,
                                  float& wz) {
  const float ddx = uf - rec.x;
  const float ddy = vf - rec.y;
  const float dist = sqrtf(ddx * ddx + ddy * ddy + EPSf);
  // branchless: w==0 contributes nothing; rec.w == 1/(z+eps)
  const float w = fmaxf(0.0f, 1.0f - dist * 0.5f) * rec.w;
  wsum += w;
  wz += w * rec.z;
  acc[0]  += w * f0.x; acc[1]  += w * f0.y;
  acc[2]  += w * f0.z; acc[3]  += w * f0.w;
  acc[4]  += w * f1.x; acc[5]  += w * f1.y;
  acc[6]  += w * f1.z; acc[7]  += w * f1.w;
  acc[8]  += w * f2.x; acc[9]  += w * f2.y;
  acc[10] += w * f2.z; acc[11] += w * f2.w;
  acc[12] += w * f3.x; acc[13] += w * f3.y;
  acc[14] += w * f3.z; acc[15] += w * f3.w;
}

// ---------------- K4: gather — 16 ch/thread, planar slices, XCD swizzle,
//     2-way unroll + sched_barrier pin (loads CANNOT be sunk -> MLP=2) ----
template <bool FSTAGED>
__global__ __launch_bounds__(256) void gather_kernel(
    const float* __restrict__ feats,  // planar (B,V,C,N), used when !FSTAGED
    const unsigned int* __restrict__ offs, const unsigned int* __restrict__ curs,
    const float4* __restrict__ binned, const float4* __restrict__ binnedF,
    float* __restrict__ out) {
  // XCD-aware swizzle: grid = 8192 = 8 XCDs x 1024. Each XCD gets one
  // contiguous chunk of "orig" = one full bv image (4 cg x 256 rows).
  const int cpx = gridDim.x >> 3;
  const int orig = (blockIdx.x & 7) * cpx + (blockIdx.x >> 3);
  const int bv = orig >> 10;
  const int cg = (orig >> 8) & 3;   // channel group: channels [cg*16, cg*16+16)
  const int vrow = orig & 255;
  const int u = threadIdx.x;

  float acc[16];
#pragma unroll
  for (int c = 0; c < 16; c++) acc[c] = 0.f;
  float wsum = 0.f, wz = 0.f;

  const float uf = (float)u, vf = (float)vrow;
  const int by_lo = max(0, vrow - 2), by_hi = min(Hd - 1, vrow + 2);
  const int bx_lo = max(0, u - 2), bx_hi = min(Wd - 1, u + 2);

  const float4* plane = binnedF + (((size_t)cg * NREC) << 2);

  for (int by = by_lo; by <= by_hi; by++) {
    const int rowb = (bv << 16) | (by << 8);
    const unsigned int s = offs[rowb + bx_lo];
    const unsigned int e = curs[rowb + bx_hi];
    if (FSTAGED) {
      unsigned int r = s;
      // 2-way unroll over INDEPENDENT records. sched_barrier(0) pins all
      // 10 loads ABOVE the compute: the scheduler cannot sink record B's
      // loads after record A's compute, so both load chains are in flight
      // together (true MLP=2). Round-13/15 showed the compiler otherwise
      // re-serializes to save registers (VGPR stayed 28-32).
      for (; r + 1 < e; r += 2) {
        const float4 recA = binned[r];
        const float4 recB = binned[r + 1];
        const float4* fsA = plane + ((size_t)r << 2);
        const float4* fsB = plane + ((size_t)(r + 1) << 2);
        const float4 a0 = fsA[0], a1 = fsA[1], a2 = fsA[2], a3 = fsA[3];
        const float4 b0 = fsB[0], b1 = fsB[1], b2 = fsB[2], b3 = fsB[3];
        __builtin_amdgcn_sched_barrier(0);
        gather_one(recA, a0, a1, a2, a3, uf, vf, acc, wsum, wz);
        gather_one(recB, b0, b1, b2, b3, uf, vf, acc, wsum, wz);
      }
      if (r < e) {
        const float4 recA = binned[r];
        const float4* fsA = plane + ((size_t)r << 2);
        const float4 a0 = fsA[0], a1 = fsA[1], a2 = fsA[2], a3 = fsA[3];
        gather_one(recA, a0, a1, a2, a3, uf, vf, acc, wsum, wz);
      }
    } else {
      for (unsigned int r = s; r < e; r++) {
        const float4 rec = binned[r];
        const float ddx = uf - rec.x;
        const float ddy = vf - rec.y;
        const float dist = sqrtf(ddx * ddx + ddy * ddy + EPSf);
        float w = 1.0f - dist * 0.5f;
        if (w > 0.f) {
          w *= 1.0f / (rec.z + EPSf);
          wsum += w;
          wz += w * rec.z;
          const int n = __float_as_int(rec.w);
          const float* fp = feats + ((size_t)bv * Cc << 16) + n;
#pragma unroll
          for (int c = 0; c < 16; c++)
            acc[c] += w * fp[(size_t)(cg * 16 + c) << 16];
        }
      }
    }
  }

  const float inv = 1.0f / (wsum + EPSf);
  const int dest = (vrow << 8) | u;
  float* ob = out + (((size_t)bv * 65) << 16) + ((size_t)(cg * 16) << 16) + dest;
#pragma unroll
  for (int c = 0; c < 16; c++) ob[(size_t)c << 16] = acc[c] * inv;
  if (cg == 0) {
    // depth plane (channel 64)
    out[(((size_t)bv * 65 + Cc) << 16) + dest] = wz * inv;
  }
}

// ---------------- fallback: round-1 atomic splat ----------------
__global__ __launch_bounds__(256) void splat_kernel(
    const float* __restrict__ feats, const float* __restrict__ depths,
    const float* __restrict__ Kmat, const float* __restrict__ srcinv,
    const float* __restrict__ dstRT, float* __restrict__ out,
    float* __restrict__ wsum) {
  const int bv = blockIdx.x >> 8;
  const int n = ((blockIdx.x & 255) << 8) | threadIdx.x;
  const int b = bv >> 2;

  __shared__ float T[16];
  if (threadIdx.x == 0) compute_T(Kmat, srcinv, dstRT, b, bv, T);
  __syncthreads();

  const float d = depths[(size_t)bv * Nn + n];
  const float gx = (float)(n & (Wd - 1));
  const float gy = (float)(n >> 8);
  const float p0 = (T[0] * gx + T[1] * gy + T[2]) * d + T[3];
  const float p1 = (T[4] * gx + T[5] * gy + T[6]) * d + T[7];
  const float z  = (T[8] * gx + T[9] * gy + T[10]) * d + T[11];
  const float ze = z + EPSf;
  const float x = p0 / ze, y = p1 / ze;
  const float zi = 1.0f / ze;
  const float px0 = rintf(x), py0 = rintf(y);
  const bool zok = (z > EPSf);

  float f[Cc];
  const float* fp = feats + (size_t)bv * Cc * Nn + n;
#pragma unroll
  for (int c = 0; c < Cc; c++) f[c] = fp[(size_t)c * Nn];

  float* outbv = out + (size_t)bv * 65 * Nn;
  float* wbv = wsum + (size_t)bv * Nn;
#pragma unroll
  for (int dy = -2; dy <= 2; dy++) {
#pragma unroll
    for (int dx = -2; dx <= 2; dx++) {
      const float px = px0 + (float)dx;
      const float py = py0 + (float)dy;
      const float ddx = px - x, ddy = py - y;
      const float dist = sqrtf(ddx * ddx + ddy * ddy + EPSf);
      float w = fmaxf(0.0f, 1.0f - dist * 0.5f);
      const bool valid = zok && (px >= 0.0f) && (px < (float)Wd) &&
                         (py >= 0.0f) && (py < (float)Hd);
      w = valid ? w * zi : 0.0f;
      if (w > 0.0f) {
        const int idx = (int)py * Wd + (int)px;
        atomicAdd(wbv + idx, w);
        atomicAdd(outbv + (size_t)Cc * Nn + idx, w * z);
#pragma unroll
        for (int c = 0; c < Cc; c++)
          atomicAdd(outbv + (size_t)c * Nn + idx, w * f[c]);
      }
    }
  }
}

__global__ __launch_bounds__(256) void norm_kernel(float* __restrict__ out,
                                                   const float* __restrict__ wsum) {
  const int t = blockIdx.x * 256 + threadIdx.x;
  const int n = t & 0xFFFF;
  const int bvc = t >> 16;
  const int bv = bvc / 65;
  const float wv = wsum[(size_t)bv * Nn + n];
  out[t] = out[t] / (wv + EPSf);
}

extern "C" void kernel_launch(void* const* d_in, const int* in_sizes, int n_in,
                              void* d_out, int out_size, void* d_ws, size_t ws_size,
                              hipStream_t stream) {
  const float* feats  = (const float*)d_in[0];
  const float* depths = (const float*)d_in[1];
  const float* Kmat   = (const float*)d_in[2];
  const float* srcinv = (const float*)d_in[4];
  const float* dstRT  = (const float*)d_in[5];
  float* out = (float*)d_out;
  char* ws = (char*)d_ws;

  if (ws_size >= NEED_MID) {
    unsigned int* counts = (unsigned int*)(ws + OFF_COUNT);
    unsigned int* offs   = (unsigned int*)(ws + OFF_OFFS);
    unsigned int* curs   = (unsigned int*)(ws + OFF_CURS);
    unsigned int* rowsum = (unsigned int*)(ws + OFF_ROWSUM);
    unsigned int* rowbase= (unsigned int*)(ws + OFF_ROWBASE);
    float4* stage1 = (float4*)(ws + OFF_STAGE1);
    float4* binned = (float4*)(ws + OFF_BINNED);
    float4* binnedF= (float4*)(ws + OFF_FT);

    hipMemsetAsync(counts, 0, (size_t)BVn * Nn * sizeof(unsigned int), stream);

    const bool staged = (ws_size >= NEED_FULL);

    project_count_kernel<<<dim3(BVn * (Nn / 256)), dim3(256), 0, stream>>>(
        depths, Kmat, srcinv, dstRT, counts, stage1);
    row_sum_kernel<<<dim3(512), dim3(256), 0, stream>>>(counts, rowsum);
    scan_rows_kernel<<<dim3(1), dim3(256), 0, stream>>>(rowsum, rowbase);
    bin_offsets_kernel<<<dim3(512), dim3(256), 0, stream>>>(counts, rowbase, offs, curs);

    if (staged) {
      fill_kernel<true><<<dim3(BVn * Nn / 256), dim3(256), 0, stream>>>(
          feats, stage1, curs, binned, binnedF);
      gather_kernel<true><<<dim3(BVn * 4 * Hd), dim3(256), 0, stream>>>(
          feats, offs, curs, binned, binnedF, out);
    } else {
      fill_kernel<false><<<dim3(BVn * Nn / 256), dim3(256), 0, stream>>>(
          feats, stage1, curs, binned, binnedF);
      gather_kernel<false><<<dim3(BVn * 4 * Hd), dim3(256), 0, stream>>>(
          feats, offs, curs, binned, binnedF, out);
    }
  } else {
    // atomic fallback (round-1 path)
    float* wsum = (float*)ws;  // (BV,N) = 2 MiB
    hipMemsetAsync(out, 0, (size_t)out_size * sizeof(float), stream);
    hipMemsetAsync(wsum, 0, (size_t)BVn * Nn * sizeof(float), stream);
    splat_kernel<<<dim3(BVn * (Nn / 256)), dim3(256), 0, stream>>>(
        feats, depths, Kmat, srcinv, dstRT, out, wsum);
    norm_kernel<<<dim3(BVn * 65 * Nn / 256), dim3(256), 0, stream>>>(out, wsum);
  }
}